// Round 3
// baseline (158.428 us; speedup 1.0000x reference)
//
#include <hip/hip_runtime.h>
#include <math.h>

#define NPTS  8192
#define BLOCK 512
#define RPB   16            // rows per block = 2 per wave * 8 waves
#define NWAVE (BLOCK/64)
#define TILE  1024
#define NTILE (NPTS/TILE)
#define K9    9
#define ALIGN_T 4.0e-4f     // (0.02)^2 ; monotone proxy for dist < 0.02

// branch-free insert v into ascending 9-list (keeps 9 smallest)
__device__ __forceinline__ void insert9(float (&d)[K9], float v) {
#pragma unroll
    for (int k = 0; k < K9; k++) {
        float lo = fminf(d[k], v);
        v = fmaxf(d[k], v);
        d[k] = lo;
    }
}

// merge partner lane's list (lane ^ o) into mine
__device__ __forceinline__ void merge_shfl(float (&d)[K9], int o) {
    float t[K9];
#pragma unroll
    for (int k = 0; k < K9; k++) t[k] = __shfl_xor(d[k], o, 64);
#pragma unroll
    for (int m = 0; m < K9; m++) insert9(d, t[m]);
}

// after this, every lane holds the global (across 64 lanes) top-9, ascending
__device__ __forceinline__ void butterfly9(float (&d)[K9]) {
#pragma unroll
    for (int o = 1; o < 64; o <<= 1) merge_shfl(d, o);
}

// acc: [0]=align_sum [1]=align_cnt [2]=flat_sum [3]=dens_sum
__global__ __launch_bounds__(BLOCK) void gsr_main(
    const float*  __restrict__ pos,
    const float*  __restrict__ rot,
    const float*  __restrict__ scl,
    const float*  __restrict__ opa,
    float* __restrict__ acc)
{
    __shared__ float4 ps[TILE];     // (x,y,z,|p|^2) 16 KB
    __shared__ float4 rs[TILE];     // rotations     16 KB
    __shared__ float  red[NWAVE][4];

    const int tid  = threadIdx.x;
    const int lane = tid & 63;
    const int wave = tid >> 6;
    const int rA = blockIdx.x * RPB + wave * 2;
    const int rB = rA + 1;

    const float xA = pos[3*rA], yA = pos[3*rA+1], zA = pos[3*rA+2];
    const float xB = pos[3*rB], yB = pos[3*rB+1], zB = pos[3*rB+2];
    const float sqA = xA*xA + yA*yA + zA*zA;
    const float sqB = xB*xB + yB*yB + zB*zB;
    const float4 qA = *(const float4*)(rot + 4*rA);
    const float4 qB = *(const float4*)(rot + 4*rB);

    float da[K9], db[K9];
#pragma unroll
    for (int k = 0; k < K9; k++) { da[k] = 1e30f; db[k] = 1e30f; }
    float thrA = 1e30f, thrB = 1e30f;
    float asum = 0.f, acnt = 0.f;

    const float4* pp = &ps[lane];
    const float4* rp = &rs[lane];

    for (int t = 0; t < NTILE; t++) {
        __syncthreads();
#pragma unroll
        for (int s = 0; s < TILE/BLOCK; s++) {
            int e = s*BLOCK + tid;
            int j = t*TILE + e;
            float xj = pos[3*j], yj = pos[3*j+1], zj = pos[3*j+2];
            ps[e] = make_float4(xj, yj, zj, xj*xj + yj*yj + zj*zj);
            rs[e] = *(const float4*)(rot + 4*j);
        }
        __syncthreads();

        const float teA = fmaxf(thrA, ALIGN_T);
        const float teB = fmaxf(thrB, ALIGN_T);
        const int selA = rA - t*TILE;   // e index of self (may be out of range)
        const int selB = rB - t*TILE;

#pragma unroll
        for (int k = 0; k < TILE/64; k++) {
            float4 p = pp[k*64];                       // one ds_read_b128 / 2 candidates
            float dotA = fmaf(xA, p.x, fmaf(yA, p.y, zA*p.z));
            float dotB = fmaf(xB, p.x, fmaf(yB, p.y, zB*p.z));
            float cA = fmaf(-2.f, dotA, sqA + p.w);    // d^2 (unclamped; monotone)
            float cB = fmaf(-2.f, dotB, sqB + p.w);
            bool iA = cA < teA;
            bool iB = cB < teB;
            if (__any(iA)) insert9(da, cA);            // extra inserts are harmless;
            if (__any(iB)) insert9(db, cB);            // skipped c >= thr can't be top-9
            if (__any(iA || iB)) {
                int e = k*64 + lane;
                bool aA = (cA < ALIGN_T) && (e != selA);
                bool aB = (cB < ALIGN_T) && (e != selB);
                if (__any(aA || aB)) {
                    float4 r = rp[k*64];
                    float dqA = fmaf(qA.x, r.x, fmaf(qA.y, r.y, fmaf(qA.z, r.z, qA.w*r.w)));
                    float dqB = fmaf(qB.x, r.x, fmaf(qB.y, r.y, fmaf(qB.z, r.z, qB.w*r.w)));
                    if (aA) { asum += 1.f - fabsf(dqA); acnt += 1.f; }
                    if (aB) { asum += 1.f - fabsf(dqB); acnt += 1.f; }
                }
            }
        }

        if (t == 0) {
            // exact global 9th after first tile -> tight filter for tiles 1..7
            butterfly9(da); butterfly9(db);
            thrA = da[8]; thrB = db[8];
        } else {
            // cheap refresh: min over lanes of each lane's 9th-best (valid upper bound)
            float tA = da[8], tB = db[8];
#pragma unroll
            for (int o = 32; o > 0; o >>= 1) {
                tA = fminf(tA, __shfl_xor(tA, o, 64));
                tB = fminf(tB, __shfl_xor(tB, o, 64));
            }
            thrA = fminf(thrA, tA);
            thrB = fminf(thrB, tB);
        }
    }

    // final exact merge across lanes
    butterfly9(da);
    butterfly9(db);

    float dens = 0.f, flat = 0.f;
    if (lane < 2) {
        int r = (lane == 0) ? rA : rB;
        float s = 0.f;
#pragma unroll
        for (int k = 1; k < K9; k++) {                 // drop min = self (~0)
            float v = (lane == 0) ? da[k] : db[k];
            s += sqrtf(fmaxf(v, 0.f) + 1e-12f);
        }
        dens = fabsf(s * 0.125f - 0.01f) * opa[r];
        float a = expf(scl[3*r]), b = expf(scl[3*r+1]), c = expf(scl[3*r+2]);
        float mn  = fminf(a, fminf(b, c));
        float mx  = fmaxf(a, fmaxf(b, c));
        float mid = fminf(fmaxf(a, b), fmaxf(fminf(a, b), c));
        float fr  = logf(mx / (mn + 1e-8f) + 1e-8f);
        float dsim = 1.f / (fabsf(mx - mid) + 0.001f);
        flat = fr + 0.1f * dsim;
    }

    float vals[4] = {asum, acnt, flat, dens};
#pragma unroll
    for (int qi = 0; qi < 4; qi++) {
        float v = vals[qi];
        for (int o = 32; o > 0; o >>= 1) v += __shfl_down(v, o, 64);
        if (lane == 0) red[wave][qi] = v;
    }
    __syncthreads();
    if (tid == 0) {
        float t0 = 0, t1 = 0, t2 = 0, t3 = 0;
        for (int w = 0; w < NWAVE; w++) {
            t0 += red[w][0]; t1 += red[w][1]; t2 += red[w][2]; t3 += red[w][3];
        }
        atomicAdd(&acc[0], t0);
        atomicAdd(&acc[1], t1);
        atomicAdd(&acc[2], t2);
        atomicAdd(&acc[3], t3);
    }
}

__global__ void gsr_final(const float* __restrict__ acc, float* __restrict__ out)
{
    float flat_loss = -acc[2] / (float)NPTS;
    float align_loss = (acc[1] > 0.f) ? (acc[0] / acc[1]) : 0.f;
    float dens_loss = acc[3] / (float)NPTS;
    out[0] = 1.0f * flat_loss + 0.5f * align_loss + 0.2f * dens_loss;
}

extern "C" void kernel_launch(void* const* d_in, const int* in_sizes, int n_in,
                              void* d_out, int out_size, void* d_ws, size_t ws_size,
                              hipStream_t stream) {
    const float* pos = (const float*)d_in[0];
    const float* rot = (const float*)d_in[1];
    const float* scl = (const float*)d_in[2];
    const float* opa = (const float*)d_in[3];
    float* acc = (float*)d_ws;

    hipMemsetAsync(acc, 0, 4 * sizeof(float), stream);
    gsr_main<<<dim3(NPTS/RPB), dim3(BLOCK), 0, stream>>>(pos, rot, scl, opa, acc);
    gsr_final<<<1, 1, 0, stream>>>(acc, (float*)d_out);
}

// Round 4
// 117.802 us; speedup vs baseline: 1.3449x; 1.3449x over previous
//
#include <hip/hip_runtime.h>
#include <math.h>

#define NPTS 8192
#define GD 8                       // grid cells per axis
#define NCELL (GD*GD*GD)           // 512
#define CELL_H (0.3f/(float)GD)    // 0.0375 > 0.02 alignment radius
#define INV_H ((float)GD/0.3f)
#define ALIGN_T 4.0e-4f            // 0.02^2
#define K9 9

#define QBLOCK 512
#define QWAVES (QBLOCK/64)         // 8
#define QGRID (NPTS/QWAVES)        // 1024

// ws layout (bytes) — requires ~308 KB of scratch
#define WS_POS    0                // float4[NPTS] (x,y,z,|p|^2) sorted
#define WS_ROT    131072           // float4[NPTS] sorted rotations
#define WS_CSTART 262144           // int[NCELL+1] cell range starts
#define WS_IDX    266240           // int[NPTS] sorted -> original index
#define WS_CNTR   299008           // unsigned int completion counter
#define WS_PART   299024           // float[QGRID*4] per-block partials

// -------- build: counting sort of points into 8^3 cells (one block) --------
__global__ __launch_bounds__(1024) void gsr_build(
    const float* __restrict__ pos,
    const float* __restrict__ rot,
    unsigned char* __restrict__ ws)
{
    float4* sPos = (float4*)(ws + WS_POS);
    float4* sRot = (float4*)(ws + WS_ROT);
    int* cellStart = (int*)(ws + WS_CSTART);
    int* sIdx = (int*)(ws + WS_IDX);
    unsigned int* counter = (unsigned int*)(ws + WS_CNTR);

    __shared__ int cnt[NCELL];
    __shared__ int scanb[NCELL];
    __shared__ int start[NCELL];

    const int tid = threadIdx.x;
    if (tid < NCELL) cnt[tid] = 0;
    if (tid == 0) *counter = 0u;     // zero the fused-final counter each call
    __syncthreads();

    float px[8], py[8], pz[8];
    int cellv[8], slotv[8];
#pragma unroll
    for (int k = 0; k < 8; k++) {
        int p = tid + k*1024;
        float x = pos[3*p+0], y = pos[3*p+1], z = pos[3*p+2];
        px[k]=x; py[k]=y; pz[k]=z;
        int ix = min((int)(x*INV_H), GD-1);
        int iy = min((int)(y*INV_H), GD-1);
        int iz = min((int)(z*INV_H), GD-1);
        int c = (ix*GD+iy)*GD+iz;
        cellv[k]=c;
        slotv[k]=atomicAdd(&cnt[c],1);
    }
    __syncthreads();
    if (tid < NCELL) scanb[tid] = cnt[tid];
    __syncthreads();
    for (int off=1; off<NCELL; off<<=1) {     // Hillis-Steele inclusive scan
        int v = 0;
        if (tid < NCELL && tid >= off) v = scanb[tid-off];
        __syncthreads();
        if (tid < NCELL) scanb[tid] += v;
        __syncthreads();
    }
    if (tid < NCELL) {
        int st = scanb[tid]-cnt[tid];         // exclusive
        start[tid]=st;
        cellStart[tid]=st;
    }
    if (tid==0) cellStart[NCELL]=NPTS;
    __syncthreads();
#pragma unroll
    for (int k=0;k<8;k++) {
        int p = tid + k*1024;
        int dst = start[cellv[k]] + slotv[k];
        float x=px[k],y=py[k],z=pz[k];
        // NOTE: identical fmaf shape as the query's dot product -> self d2 == 0 exactly
        float w = fmaf(x,x,fmaf(y,y,z*z));
        sPos[dst]=make_float4(x,y,z,w);
        sRot[dst]=*(const float4*)(rot+4*p);
        sIdx[dst]=p;
    }
}

__device__ __forceinline__ void insert9(float (&d)[K9], float v) {
#pragma unroll
    for (int k=0;k<K9;k++){ float lo=fminf(d[k],v); v=fmaxf(d[k],v); d[k]=lo; }
}

// -------- query: one wave per (sorted) row; expanding-ring exact KNN --------
__global__ __launch_bounds__(QBLOCK, 4) void gsr_query(
    const float* __restrict__ scl,
    const float* __restrict__ opa,
    unsigned char* __restrict__ ws,
    float* __restrict__ out)
{
    const float4* sPos = (const float4*)(ws + WS_POS);
    const float4* sRot = (const float4*)(ws + WS_ROT);
    const int* cellStart = (const int*)(ws + WS_CSTART);
    const int* sIdx = (const int*)(ws + WS_IDX);
    unsigned int* counter = (unsigned int*)(ws + WS_CNTR);
    float* partials = (float*)(ws + WS_PART);

    __shared__ float red[QWAVES][4];
    __shared__ int lastflag;

    const int tid = threadIdx.x;
    const int lane = tid & 63;
    const int wv = tid >> 6;
    const int s = blockIdx.x*QWAVES + wv;     // sorted slot = row

    const float4 P = sPos[s];
    const float4 Q = sRot[s];
    const float sA = P.w;
    const int cx = min((int)(P.x*INV_H),GD-1);
    const int cy = min((int)(P.y*INV_H),GD-1);
    const int cz = min((int)(P.z*INV_H),GD-1);

    float d[K9];
#pragma unroll
    for (int k=0;k<K9;k++) d[k]=1e30f;
    float asum=0.f, acnt=0.f, s8=0.f;

    for (int r=1; r<=GD; r++) {
        const int xlo=max(cx-r,0), xhi=min(cx+r,GD-1);
        const int ylo=max(cy-r,0), yhi=min(cy+r,GD-1);
        const bool ring1 = (r==1);
        for (int jx=xlo; jx<=xhi; jx++) {
            const int adx = (jx>cx)?(jx-cx):(cx-jx);
            for (int jy=ylo; jy<=yhi; jy++) {
                const int ady=(jy>cy)?(jy-cy):(cy-jy);
                const int b=(jx*GD+jy)*GD;
                // new cells at ring r only (Chebyshev == r; ring1 takes Cheb<=1)
                int rs0=-1,re0=-1, rs1=-1,re1=-1;
                if (ring1 || adx==r || ady==r) {
                    rs0 = cellStart[b+max(cz-r,0)];
                    re0 = cellStart[b+min(cz+r,GD-1)+1];
                } else {
                    if (cz-r>=0)    { rs0=cellStart[b+cz-r]; re0=cellStart[b+cz-r+1]; }
                    if (cz+r<=GD-1) { rs1=cellStart[b+cz+r]; re1=cellStart[b+cz+r+1]; }
                }
#pragma unroll
                for (int pass=0; pass<2; pass++) {
                    const int rs = pass? rs1: rs0, re = pass? re1: re0;
                    for (int o=rs+lane; o<re; o+=64) {
                        float4 p = sPos[o];
                        float dt = fmaf(P.x,p.x,fmaf(P.y,p.y,P.z*p.z));
                        float c = fmaf(-2.f,dt,sA+p.w);   // d^2 (self == 0 exactly)
                        insert9(d,c);
                        if (ring1) {                       // ring>=2 cells are >= h > 0.02 away
                            bool a = (c<ALIGN_T) & (o!=s);
                            float4 rt = sRot[o];
                            float dq = fmaf(Q.x,rt.x,fmaf(Q.y,rt.y,fmaf(Q.z,rt.z,Q.w*rt.w)));
                            asum += a ? (1.f-fabsf(dq)) : 0.f;
                            acnt += a ? 1.f : 0.f;
                        }
                    }
                }
            }
        }
        // cross-lane merge via 9x extract-min (on copies), then coverage test
        float t[K9];
#pragma unroll
        for (int k=0;k<K9;k++) t[k]=d[k];
        float ssum=0.f, d9=0.f;
#pragma unroll
        for (int k=0;k<K9;k++) {
            float m=t[0];
#pragma unroll
            for (int o=32;o>0;o>>=1) m=fminf(m,__shfl_xor(m,o,64));
            unsigned long long msk=__ballot(t[0]==m);
            int fl=(int)__ffsll((long long)msk)-1;
            if (lane==fl) {                    // pop from first owner only
#pragma unroll
                for (int q2=0;q2<K9-1;q2++) t[q2]=t[q2+1];
                t[K9-1]=1e30f;
            }
            if (k>=1) ssum += sqrtf(fmaxf(m,0.f)+1e-12f);  // ranks 1..8 (drop self)
            d9=m;
        }
        s8=ssum;
        // exact coverage radius of the scanned box (interior faces only;
        // clipped faces touch the domain boundary -> nothing beyond them)
        float cov=1e30f;
        if (cx-r>0)    cov=fminf(cov, P.x-(float)(cx-r)*CELL_H);
        if (cx+r<GD-1) cov=fminf(cov, (float)(cx+r+1)*CELL_H-P.x);
        if (cy-r>0)    cov=fminf(cov, P.y-(float)(cy-r)*CELL_H);
        if (cy+r<GD-1) cov=fminf(cov, (float)(cy+r+1)*CELL_H-P.y);
        if (cz-r>0)    cov=fminf(cov, P.z-(float)(cz-r)*CELL_H);
        if (cz+r<GD-1) cov=fminf(cov, (float)(cz+r+1)*CELL_H-P.z);
        if (d9 <= cov*cov) break;              // 9th-NN provably inside scanned region
    }

    float flat=0.f, dens=0.f;
    if (lane==0) {
        int i = sIdx[s];
        dens = fabsf(s8*0.125f-0.01f)*opa[i];
        float ea=expf(scl[3*i]), eb=expf(scl[3*i+1]), ec=expf(scl[3*i+2]);
        float mn=fminf(ea,fminf(eb,ec));
        float mx=fmaxf(ea,fmaxf(eb,ec));
        float md=fminf(fmaxf(ea,eb),fmaxf(fminf(ea,eb),ec));
        flat = logf(mx/(mn+1e-8f)+1e-8f) + 0.1f/(fabsf(mx-md)+0.001f);
    }

    // block reduction of (asum, acnt, flat, dens)
    float vals[4] = {asum, acnt, flat, dens};
#pragma unroll
    for (int qi=0; qi<4; qi++){
        float v = vals[qi];
        for (int o=32;o>0;o>>=1) v += __shfl_down(v,o,64);
        if (lane==0) red[wv][qi]=v;
    }
    __syncthreads();
    if (tid == 0) {
        float t0=0,t1=0,t2=0,t3=0;
        for (int w=0;w<QWAVES;w++){t0+=red[w][0];t1+=red[w][1];t2+=red[w][2];t3+=red[w][3];}
        *(float4*)(partials + blockIdx.x*4) = make_float4(t0,t1,t2,t3);
        __threadfence();                               // release partial
        unsigned int old = atomicAdd(counter, 1u);
        lastflag = (old == QGRID-1) ? 1 : 0;
    }
    __syncthreads();
    if (lastflag && wv == 0) {                         // fused final reduction
        __threadfence();                               // acquire
        float t0=0,t1=0,t2=0,t3=0;
        for (int b = lane; b < QGRID; b += 64) {
            float4 pv = *(const float4*)(partials + b*4);
            t0+=pv.x; t1+=pv.y; t2+=pv.z; t3+=pv.w;
        }
        for (int o=32;o>0;o>>=1){
            t0+=__shfl_down(t0,o,64); t1+=__shfl_down(t1,o,64);
            t2+=__shfl_down(t2,o,64); t3+=__shfl_down(t3,o,64);
        }
        if (lane==0) {
            float flat_loss = -t2 / (float)NPTS;
            float align_loss = (t1 > 0.f) ? (t0/t1) : 0.f;
            float dens_loss = t3 / (float)NPTS;
            out[0] = 1.0f*flat_loss + 0.5f*align_loss + 0.2f*dens_loss;
        }
    }
}

extern "C" void kernel_launch(void* const* d_in, const int* in_sizes, int n_in,
                              void* d_out, int out_size, void* d_ws, size_t ws_size,
                              hipStream_t stream) {
    const float* pos = (const float*)d_in[0];
    const float* rot = (const float*)d_in[1];
    const float* scl = (const float*)d_in[2];
    const float* opa = (const float*)d_in[3];
    unsigned char* ws = (unsigned char*)d_ws;

    gsr_build<<<1, 1024, 0, stream>>>(pos, rot, ws);
    gsr_query<<<QGRID, QBLOCK, 0, stream>>>(scl, opa, ws, (float*)d_out);
}

// Round 5
// 101.492 us; speedup vs baseline: 1.5610x; 1.1607x over previous
//
#include <hip/hip_runtime.h>
#include <math.h>

#define NPTS 8192
#define GD 8
#define NCELL (GD*GD*GD)           // 512
#define CELL_H (0.3f/(float)GD)    // 0.0375 > 0.02 alignment radius
#define INV_H ((float)GD/0.3f)
#define ALIGN_T 4.0e-4f            // 0.02^2
#define K9 9

#define QBLOCK 512
#define QWAVES (QBLOCK/64)         // 8
#define QGRID (NPTS/QWAVES)        // 1024

// ws layout (bytes), total ~350 KB
#define WS_POS    0                // float4[NPTS] sorted (x,y,z,|p|^2)
#define WS_ROT    131072           // float4[NPTS] sorted rotations
#define WS_CSTART 262144           // int[NCELL+1]
#define WS_IDX    266240           // int[NPTS] sorted -> original
#define WS_CNTR   299008           // unsigned int completion counter
#define WS_PART   299024           // float4[QGRID] partials (16 KB)
#define WS_GCNT   315424           // int[NCELL] global cell counts
#define WS_AUX    317472           // int[NPTS] packed (cell | slot<<9)

// ---------------- build stage 1: count (32 blocks) ----------------
__global__ __launch_bounds__(256) void gsr_count(
    const float* __restrict__ pos, unsigned char* __restrict__ ws)
{
    int* gcnt = (int*)(ws + WS_GCNT);
    int* aux  = (int*)(ws + WS_AUX);
    int p = blockIdx.x*256 + threadIdx.x;
    float x = pos[3*p], y = pos[3*p+1], z = pos[3*p+2];
    int ix = min((int)(x*INV_H), GD-1);
    int iy = min((int)(y*INV_H), GD-1);
    int iz = min((int)(z*INV_H), GD-1);
    int c = (ix*GD+iy)*GD+iz;
    int slot = atomicAdd(&gcnt[c], 1);
    aux[p] = c | (slot << 9);
}

// ---------------- build stage 2: scan (1 block) ----------------
__global__ __launch_bounds__(NCELL) void gsr_scan(unsigned char* __restrict__ ws)
{
    const int* gcnt = (const int*)(ws + WS_GCNT);
    int* cellStart  = (int*)(ws + WS_CSTART);
    unsigned int* counter = (unsigned int*)(ws + WS_CNTR);
    __shared__ int sb[NCELL];
    int t = threadIdx.x;
    sb[t] = gcnt[t];
    __syncthreads();
    for (int off = 1; off < NCELL; off <<= 1) {
        int v = (t >= off) ? sb[t-off] : 0;
        __syncthreads();
        sb[t] += v;
        __syncthreads();
    }
    cellStart[t+1] = sb[t];          // inclusive -> start[t+1]
    if (t == 0) { cellStart[0] = 0; *counter = 0u; }
}

// ---------------- build stage 3: scatter (32 blocks) ----------------
__global__ __launch_bounds__(256) void gsr_scatter(
    const float* __restrict__ pos, const float* __restrict__ rot,
    unsigned char* __restrict__ ws)
{
    float4* sPos = (float4*)(ws + WS_POS);
    float4* sRot = (float4*)(ws + WS_ROT);
    const int* cellStart = (const int*)(ws + WS_CSTART);
    int* sIdx = (int*)(ws + WS_IDX);
    const int* aux = (const int*)(ws + WS_AUX);
    int p = blockIdx.x*256 + threadIdx.x;
    int a = aux[p];
    int c = a & (NCELL-1);
    int slot = a >> 9;
    int dst = cellStart[c] + slot;
    float x = pos[3*p], y = pos[3*p+1], z = pos[3*p+2];
    // identical fmaf shape as query dot product -> self d2 == 0 exactly
    float w = fmaf(x, x, fmaf(y, y, z*z));
    sPos[dst] = make_float4(x, y, z, w);
    sRot[dst] = *(const float4*)(rot + 4*p);
    sIdx[dst] = p;
}

__device__ __forceinline__ void insert9(float (&d)[K9], float v) {
#pragma unroll
    for (int k = 0; k < K9; k++) { float lo = fminf(d[k], v); v = fmaxf(d[k], v); d[k] = lo; }
}

// exact wave-wide top-9 statistics: s8 = sum sqrt(ranks 1..8), d9 = 9th smallest
__device__ __forceinline__ void wave_merge9(const float (&d)[K9], int lane,
                                            float& s8, float& d9) {
    float t[K9];
#pragma unroll
    for (int k = 0; k < K9; k++) t[k] = d[k];
    float ssum = 0.f, m = 0.f;
#pragma unroll
    for (int k = 0; k < K9; k++) {
        m = t[0];
#pragma unroll
        for (int o = 32; o > 0; o >>= 1) m = fminf(m, __shfl_xor(m, o, 64));
        unsigned long long msk = __ballot(t[0] == m);
        int fl = (int)__ffsll((long long)msk) - 1;
        if (lane == fl) {
#pragma unroll
            for (int q = 0; q < K9-1; q++) t[q] = t[q+1];
            t[K9-1] = 1e30f;
        }
        if (k >= 1) ssum += sqrtf(fmaxf(m, 0.f) + 1e-12f);
    }
    s8 = ssum; d9 = m;
}

__device__ __forceinline__ int rfl_i(int v) { return __builtin_amdgcn_readfirstlane(v); }
__device__ __forceinline__ float rfl_f(float v) {
    return __int_as_float(__builtin_amdgcn_readfirstlane(__float_as_int(v)));
}

// ---------------- query: one wave per sorted row ----------------
__global__ __launch_bounds__(QBLOCK) void gsr_query(
    const float* __restrict__ scl,
    const float* __restrict__ opa,
    unsigned char* __restrict__ ws,
    float* __restrict__ out)
{
    const float4* sPos = (const float4*)(ws + WS_POS);
    const float4* sRot = (const float4*)(ws + WS_ROT);
    const int* cellStart = (const int*)(ws + WS_CSTART);
    const int* sIdx = (const int*)(ws + WS_IDX);
    unsigned int* counter = (unsigned int*)(ws + WS_CNTR);
    float* partials = (float*)(ws + WS_PART);

    __shared__ float red[QWAVES][4];
    __shared__ int lastflag;

    const int tid = threadIdx.x;
    const int lane = tid & 63;
    const int wv = tid >> 6;
    const int s = blockIdx.x*QWAVES + wv;     // sorted slot = row (uniform)

    // scalarize row data: SGPR coords -> scalar bounds -> s_load'ed cellStart
    const float4 Pv = sPos[s];
    const float Px = rfl_f(Pv.x), Py = rfl_f(Pv.y), Pz = rfl_f(Pv.z), Pw = rfl_f(Pv.w);
    const float4 Q = sRot[s];
    const int cx = rfl_i(min((int)(Px*INV_H), GD-1));
    const int cy = rfl_i(min((int)(Py*INV_H), GD-1));
    const int cz = rfl_i(min((int)(Pz*INV_H), GD-1));
    const int zlo = max(cz-1, 0), zhi = min(cz+1, GD-1);

    float d[K9];
#pragma unroll
    for (int k = 0; k < K9; k++) d[k] = 1e30f;
    float asum = 0.f, acnt = 0.f;

    // ---- ring-1 fast path: fully unrolled 3x3 columns, scalar bounds ----
#pragma unroll
    for (int dx = -1; dx <= 1; dx++) {
        const int jx = cx + dx;
        if (jx < 0 || jx > GD-1) continue;    // uniform scalar branch
#pragma unroll
        for (int dy = -1; dy <= 1; dy++) {
            const int jy = cy + dy;
            if (jy < 0 || jy > GD-1) continue;
            const int b = (jx*GD + jy)*GD;
            const int rs = cellStart[b + zlo];      // s_load (uniform addr)
            const int re = cellStart[b + zhi + 1];
            for (int o = rs + lane; o < re; o += 64) {
                float4 p = sPos[o];
                float dt = fmaf(Px, p.x, fmaf(Py, p.y, Pz*p.z));
                float c = fmaf(-2.f, dt, Pw + p.w);     // d^2, self == 0 exact
                insert9(d, c);
                bool a = (c < ALIGN_T) & (o != s);
                if (a) {
                    float4 rt = sRot[o];
                    float dq = fmaf(Q.x, rt.x, fmaf(Q.y, rt.y, fmaf(Q.z, rt.z, Q.w*rt.w)));
                    asum += 1.f - fabsf(dq);
                    acnt += 1.f;
                }
            }
        }
    }

    float s8, d9;
    wave_merge9(d, lane, s8, d9);

    // coverage radius of ring-1 box (interior faces only)
    float cov = 1e30f;
    if (cx-1 > 0)    cov = fminf(cov, Px - (float)(cx-1)*CELL_H);
    if (cx+1 < GD-1) cov = fminf(cov, (float)(cx+2)*CELL_H - Px);
    if (cy-1 > 0)    cov = fminf(cov, Py - (float)(cy-1)*CELL_H);
    if (cy+1 < GD-1) cov = fminf(cov, (float)(cy+2)*CELL_H - Py);
    if (cz-1 > 0)    cov = fminf(cov, Pz - (float)(cz-1)*CELL_H);
    if (cz+1 < GD-1) cov = fminf(cov, (float)(cz+2)*CELL_H - Pz);

    if (!(d9 <= cov*cov)) {
        // ---- cold exact fallback: expanding Chebyshev shells r>=2 ----
        for (int r = 2; r <= GD; r++) {
            const int xlo2 = max(cx-r,0), xhi2 = min(cx+r,GD-1);
            const int ylo2 = max(cy-r,0), yhi2 = min(cy+r,GD-1);
            for (int jx = xlo2; jx <= xhi2; jx++) {
                const int adx = (jx>cx)?(jx-cx):(cx-jx);
                for (int jy = ylo2; jy <= yhi2; jy++) {
                    const int ady = (jy>cy)?(jy-cy):(cy-jy);
                    const int b = (jx*GD+jy)*GD;
                    int rs0=-1,re0=-1, rs1=-1,re1=-1;
                    if (adx==r || ady==r) {
                        rs0 = cellStart[b+max(cz-r,0)];
                        re0 = cellStart[b+min(cz+r,GD-1)+1];
                    } else {
                        if (cz-r >= 0)    { rs0=cellStart[b+cz-r]; re0=cellStart[b+cz-r+1]; }
                        if (cz+r <= GD-1) { rs1=cellStart[b+cz+r]; re1=cellStart[b+cz+r+1]; }
                    }
#pragma unroll
                    for (int pass = 0; pass < 2; pass++) {
                        const int rs = pass? rs1: rs0, re = pass? re1: re0;
                        for (int o = rs + lane; o < re; o += 64) {
                            float4 p = sPos[o];
                            float dt = fmaf(Px, p.x, fmaf(Py, p.y, Pz*p.z));
                            float c = fmaf(-2.f, dt, Pw + p.w);
                            insert9(d, c);
                        }
                    }
                }
            }
            wave_merge9(d, lane, s8, d9);
            float cv = 1e30f;
            if (cx-r > 0)    cv = fminf(cv, Px - (float)(cx-r)*CELL_H);
            if (cx+r < GD-1) cv = fminf(cv, (float)(cx+r+1)*CELL_H - Px);
            if (cy-r > 0)    cv = fminf(cv, Py - (float)(cy-r)*CELL_H);
            if (cy+r < GD-1) cv = fminf(cv, (float)(cy+r+1)*CELL_H - Py);
            if (cz-r > 0)    cv = fminf(cv, Pz - (float)(cz-r)*CELL_H);
            if (cz+r < GD-1) cv = fminf(cv, (float)(cz+r+1)*CELL_H - Pz);
            if (d9 <= cv*cv) break;
        }
    }

    float flat = 0.f, dens = 0.f;
    if (lane == 0) {
        int i = sIdx[s];
        dens = fabsf(s8*0.125f - 0.01f) * opa[i];
        float ea = expf(scl[3*i]), eb = expf(scl[3*i+1]), ec = expf(scl[3*i+2]);
        float mn = fminf(ea, fminf(eb, ec));
        float mx = fmaxf(ea, fmaxf(eb, ec));
        float md = fminf(fmaxf(ea, eb), fmaxf(fminf(ea, eb), ec));
        flat = logf(mx/(mn+1e-8f)+1e-8f) + 0.1f/(fabsf(mx-md)+0.001f);
    }

    float vals[4] = {asum, acnt, flat, dens};
#pragma unroll
    for (int qi = 0; qi < 4; qi++) {
        float v = vals[qi];
        for (int o = 32; o > 0; o >>= 1) v += __shfl_down(v, o, 64);
        if (lane == 0) red[wv][qi] = v;
    }
    __syncthreads();
    if (tid == 0) {
        float t0=0,t1=0,t2=0,t3=0;
        for (int w = 0; w < QWAVES; w++) { t0+=red[w][0]; t1+=red[w][1]; t2+=red[w][2]; t3+=red[w][3]; }
        *(float4*)(partials + blockIdx.x*4) = make_float4(t0,t1,t2,t3);
        __threadfence();
        unsigned int old = atomicAdd(counter, 1u);
        lastflag = (old == QGRID-1) ? 1 : 0;
    }
    __syncthreads();
    if (lastflag && wv == 0) {
        __threadfence();
        float t0=0,t1=0,t2=0,t3=0;
        for (int b = lane; b < QGRID; b += 64) {
            float4 pv = *(const float4*)(partials + b*4);
            t0+=pv.x; t1+=pv.y; t2+=pv.z; t3+=pv.w;
        }
        for (int o = 32; o > 0; o >>= 1) {
            t0+=__shfl_down(t0,o,64); t1+=__shfl_down(t1,o,64);
            t2+=__shfl_down(t2,o,64); t3+=__shfl_down(t3,o,64);
        }
        if (lane == 0) {
            float flat_loss = -t2 / (float)NPTS;
            float align_loss = (t1 > 0.f) ? (t0/t1) : 0.f;
            float dens_loss = t3 / (float)NPTS;
            out[0] = 1.0f*flat_loss + 0.5f*align_loss + 0.2f*dens_loss;
        }
    }
}

extern "C" void kernel_launch(void* const* d_in, const int* in_sizes, int n_in,
                              void* d_out, int out_size, void* d_ws, size_t ws_size,
                              hipStream_t stream) {
    const float* pos = (const float*)d_in[0];
    const float* rot = (const float*)d_in[1];
    const float* scl = (const float*)d_in[2];
    const float* opa = (const float*)d_in[3];
    unsigned char* ws = (unsigned char*)d_ws;

    hipMemsetAsync(ws + WS_GCNT, 0, NCELL*sizeof(int), stream);
    gsr_count  <<<NPTS/256, 256, 0, stream>>>(pos, ws);
    gsr_scan   <<<1, NCELL, 0, stream>>>(ws);
    gsr_scatter<<<NPTS/256, 256, 0, stream>>>(pos, rot, ws);
    gsr_query  <<<QGRID, QBLOCK, 0, stream>>>(scl, opa, ws, (float*)d_out);
}